// Round 1
// baseline (669.703 us; speedup 1.0000x reference)
//
#include <hip/hip_runtime.h>

// GAT encoder, fused: B=8192 graphs (S=1024 scenes x T=8 steps), N=64 nodes, F=64.
// Layer0: masked-instnorm -> h@W0cat(64x64) -> 4-head attn(fmid=16) -> +b0, ELU, concat
// Layer1: masked-instnorm -> h@W1(64x64)    -> 1-head attn(fout=64) -> +b1
// One 256-thread block per graph; all tiles in LDS. fp32 throughout (no fp32 MFMA on CDNA4).

#define NEGV -1e12f

__global__ __launch_bounds__(256) void gat_fused(
    const float* __restrict__ x, const int* __restrict__ fhi,
    const float* __restrict__ w0g, const float* __restrict__ as0,
    const float* __restrict__ ad0, const float* __restrict__ b0g,
    const float* __restrict__ w1g, const float* __restrict__ as1,
    const float* __restrict__ ad1, const float* __restrict__ b1g,
    float* __restrict__ out)
{
    const int b = blockIdx.x;
    const int scene = b >> 3;   // b / T
    const int tt = b & 7;       // b % T
    const int tid = threadIdx.x;

    // 68-float row stride: rows 16B-aligned (68*4=272, %16==0) for b128 LDS ops.
    __shared__ float h[64][68];     // features (in-place normed); later reused for outputs
    __shared__ float hp[64][68];    // h_prime
    __shared__ float W[64][64];     // staged weights (layer0 concat-transposed, layer1 direct)
    __shared__ float sarr[4][64];   // per-head src scores
    __shared__ float darr[4][64];   // per-head dst scores
    __shared__ float redA[4][64];   // reduction partials
    __shared__ float maskv[64];
    __shared__ float meanv[64];
    __shared__ float rstdv[64];
    __shared__ float asv[64];       // a_src (flat head*16+o for L0; [64] for L1)
    __shared__ float adv[64];
    __shared__ float bias0[16];
    __shared__ float bias1[64];
    __shared__ float cntv;

    // ---------------- load x tile, weights, vectors, mask ----------------
    {
        const float* xb = x + (size_t)b * 4096;
        #pragma unroll
        for (int k = 0; k < 4; ++k) {
            int idx = k * 1024 + tid * 4;
            float4 v = *(const float4*)(xb + idx);
            int n = idx >> 6, c = idx & 63;
            h[n][c + 0] = v.x; h[n][c + 1] = v.y; h[n][c + 2] = v.z; h[n][c + 3] = v.w;
        }
    }
    for (int idx = tid; idx < 4096; idx += 256) {
        // w0 is [H=4][F=64][O=16]; want W[f][h*16+o]
        int hh = idx >> 10;
        int f  = (idx >> 4) & 63;
        int o  = idx & 15;
        W[f][hh * 16 + o] = w0g[idx];
    }
    if (tid < 64)                    { asv[tid] = as0[tid]; adv[tid] = ad0[tid]; }
    else if (tid < 128)              { bias1[tid - 64] = b1g[tid - 64]; }
    else if (tid < 144)              { bias0[tid - 128] = b0g[tid - 128]; }
    if (tid >= 192) {
        int n = tid - 192;
        maskv[n] = (fhi[scene * 64 + n] <= tt) ? 1.0f : 0.0f;
    }
    __syncthreads();

    // ---------------- masked instance norm over h (in place) ----------------
    auto do_norm = [&]() {
        const int g = tid >> 6, c = tid & 63;
        {   // pass 1: masked sum per channel
            float sum = 0.f;
            #pragma unroll
            for (int k = 0; k < 16; ++k) {
                int n = g * 16 + k;
                sum += h[n][c] * maskv[n];
            }
            redA[g][c] = sum;
        }
        __syncthreads();
        if (tid < 64) {
            float cnt = 0.f;
            #pragma unroll
            for (int m = 0; m < 64; ++m) cnt += maskv[m];
            if (cnt < 0.5f) cnt = 1.0f;
            if (tid == 0) cntv = cnt;
            meanv[tid] = (redA[0][tid] + redA[1][tid] + redA[2][tid] + redA[3][tid]) / cnt;
        }
        __syncthreads();
        {   // pass 2: masked centered squares (two-pass: exact var=0 when cnt==1)
            float mean = meanv[c];
            float sq = 0.f;
            #pragma unroll
            for (int k = 0; k < 16; ++k) {
                int n = g * 16 + k;
                float dv = (h[n][c] - mean) * maskv[n];
                sq += dv * dv;
            }
            redA[g][c] = sq;
        }
        __syncthreads();
        if (tid < 64) {
            float var = (redA[0][tid] + redA[1][tid] + redA[2][tid] + redA[3][tid]) / cntv;
            rstdv[tid] = rsqrtf(var + 1e-5f);
        }
        __syncthreads();
        #pragma unroll
        for (int k = 0; k < 16; ++k) {
            int idx = k * 256 + tid;
            int n = idx >> 6, cc = idx & 63;
            h[n][cc] = (h[n][cc] - meanv[cc]) * rstdv[cc];
        }
        __syncthreads();
    };

    // ---------------- hp = h @ W  (64x64 @ 64x64) ----------------
    auto do_matmul = [&]() {
        const int n = tid & 63;
        const int jb = (tid >> 6) * 16;
        float acc[16];
        #pragma unroll
        for (int o = 0; o < 16; ++o) acc[o] = 0.f;
        for (int f = 0; f < 64; f += 4) {
            float4 hv = *(const float4*)&h[n][f];
            float hq[4] = {hv.x, hv.y, hv.z, hv.w};
            #pragma unroll
            for (int q = 0; q < 4; ++q) {
                const float* wr = &W[f + q][jb];
                float hs = hq[q];
                #pragma unroll
                for (int o = 0; o < 16; ++o) acc[o] += hs * wr[o];
            }
        }
        #pragma unroll
        for (int o = 0; o < 16; ++o) hp[n][jb + o] = acc[o];
        __syncthreads();
    };

    // ---------------- attention + aggregate; writes results into h ----------------
    auto do_attn = [&](int layer) {
        const int grp = tid >> 6, n = tid & 63;
        const int cb = grp * 16;
        const int hidx = (layer == 0) ? grp : 0;
        const float s = sarr[hidx][n];
        const float mymask = maskv[n];
        // pass 1: row max (lrelu applied before mask, as in reference)
        float rowmax = NEGV;
        for (int m = 0; m < 64; ++m) {
            float v = s + darr[hidx][m];
            v = (v < 0.f) ? 0.2f * v : v;
            v = (mymask * maskv[m] > 0.f) ? v : NEGV;
            rowmax = fmaxf(rowmax, v);
        }
        // pass 2: exp, denom, weighted aggregate of hp columns [cb, cb+16)
        float denom = 0.f;
        float acc[16];
        #pragma unroll
        for (int o = 0; o < 16; ++o) acc[o] = 0.f;
        for (int m = 0; m < 64; ++m) {
            float v = s + darr[hidx][m];
            v = (v < 0.f) ? 0.2f * v : v;
            v = (mymask * maskv[m] > 0.f) ? v : NEGV;
            float e = __expf(v - rowmax);   // fully-masked row: all e=1 -> uniform 1/64
            denom += e;
            const float* hrow = &hp[m][cb];
            #pragma unroll
            for (int o = 0; o < 16; ++o) acc[o] += e * hrow[o];
        }
        float inv = 1.0f / denom;
        if (layer == 0) {
            #pragma unroll
            for (int o = 0; o < 16; ++o) {
                float res = acc[o] * inv + bias0[o];
                res = (res > 0.f) ? res : (__expf(res) - 1.0f);  // ELU
                h[n][cb + o] = res;  // concat heads along feature dim
            }
        } else {
            #pragma unroll
            for (int o = 0; o < 16; ++o) {
                h[n][cb + o] = acc[o] * inv + bias1[cb + o];     // no activation
            }
        }
        __syncthreads();
    };

    // ================= layer 0 =================
    do_norm();
    do_matmul();
    {   // s/d per head: 16-dim dots
        const int head = tid >> 6, n = tid & 63, cb = head * 16;
        float sv = 0.f, dv = 0.f;
        #pragma unroll
        for (int o = 0; o < 16; ++o) {
            float v = hp[n][cb + o];
            sv += v * asv[cb + o];
            dv += v * adv[cb + o];
        }
        sarr[head][n] = sv;
        darr[head][n] = dv;
    }
    __syncthreads();
    do_attn(0);   // h now holds elu(concat heads)

    // ================= layer 1 =================
    // reload weights/vectors (W not read again until do_matmul, after several barriers)
    for (int idx = tid; idx < 4096; idx += 256) {
        W[idx >> 6][idx & 63] = w1g[idx];
    }
    if (tid < 64) { asv[tid] = as1[tid]; adv[tid] = ad1[tid]; }
    do_norm();
    do_matmul();
    if (tid < 128) {   // s/d single head: 64-dim dots
        const int n = tid & 63;
        float a2 = 0.f;
        if (tid < 64) {
            #pragma unroll
            for (int o = 0; o < 64; ++o) a2 += hp[n][o] * asv[o];
            sarr[0][n] = a2;
        } else {
            #pragma unroll
            for (int o = 0; o < 64; ++o) a2 += hp[n][o] * adv[o];
            darr[0][n] = a2;
        }
    }
    __syncthreads();
    do_attn(1);   // h now holds final out (+b1)

    // ---------------- coalesced store ----------------
    {
        float* ob = out + (size_t)b * 4096;
        #pragma unroll
        for (int k = 0; k < 4; ++k) {
            int idx = k * 1024 + tid * 4;
            int n = idx >> 6, c = idx & 63;
            float4 v;
            v.x = h[n][c + 0]; v.y = h[n][c + 1]; v.z = h[n][c + 2]; v.w = h[n][c + 3];
            *(float4*)(ob + idx) = v;
        }
    }
}

extern "C" void kernel_launch(void* const* d_in, const int* in_sizes, int n_in,
                              void* d_out, int out_size, void* d_ws, size_t ws_size,
                              hipStream_t stream)
{
    const float* x   = (const float*)d_in[0];
    const int*   fhi = (const int*)d_in[1];
    const float* w0  = (const float*)d_in[2];
    const float* as0 = (const float*)d_in[3];
    const float* ad0 = (const float*)d_in[4];
    const float* b0  = (const float*)d_in[5];
    const float* w1  = (const float*)d_in[6];
    const float* as1 = (const float*)d_in[7];
    const float* ad1 = (const float*)d_in[8];
    const float* b1  = (const float*)d_in[9];
    float* o = (float*)d_out;
    hipLaunchKernelGGL(gat_fused, dim3(8192), dim3(256), 0, stream,
                       x, fhi, w0, as0, ad0, b0, w1, as1, ad1, b1, o);
}